// Round 6
// baseline (209.922 us; speedup 1.0000x reference)
//
#include <hip/hip_runtime.h>

#define HW 1659      // 21*79
#define PADID 4096
#define EMB 20
#define HID 32
#define MAXLEN 64

// ---------------- Kernel 1: presence bytes -> scan -> bag -> emb gather --------
// (unchanged from R4 — proven)
__global__ __launch_bounds__(256) void bag_emb_kernel(
    const int* __restrict__ chars, const int* __restrict__ colors,
    const float* __restrict__ emb_table,
    float* __restrict__ out_emb, float* __restrict__ out_bag)
{
    __shared__ unsigned char pres[4096];
    __shared__ int bagl[64];
    __shared__ int wsum[4];

    const int b   = blockIdx.x;
    const int tid = threadIdx.x;
    const int lane = tid & 63;
    const int wv   = tid >> 6;

    ((uint4*)pres)[tid] = make_uint4(0u, 0u, 0u, 0u);
    if (tid < 64) bagl[tid] = PADID;
    __syncthreads();

    const int base = b * HW;
    const int pe = (4 - (base & 3)) & 3;          // peel to 16B alignment
    if (tid < pe) {
        int g = (chars[base + tid] << 4) + colors[base + tid];
        pres[g] = 1;
    }
    const int nv = (HW - pe) >> 2;
    const int nt = HW - pe - (nv << 2);
    const int4* c4 = (const int4*)(chars + base + pe);
    const int4* k4 = (const int4*)(colors + base + pe);
    for (int v = tid; v < nv; v += 256) {
        int4 c = c4[v], k = k4[v];
        pres[(c.x << 4) + k.x] = 1;
        pres[(c.y << 4) + k.y] = 1;
        pres[(c.z << 4) + k.z] = 1;
        pres[(c.w << 4) + k.w] = 1;
    }
    if (tid < nt) {
        int i = base + pe + (nv << 2) + tid;
        pres[(chars[i] << 4) + colors[i]] = 1;
    }
    __syncthreads();

    uint4 w4 = ((const uint4*)pres)[tid];
    const unsigned M = 0x01010101u;
    int cnt = __popc(w4.x & M) + __popc(w4.y & M)
            + __popc(w4.z & M) + __popc(w4.w & M);

    int pre = cnt;
#pragma unroll
    for (int d = 1; d < 64; d <<= 1) {
        int v = __shfl_up(pre, d, 64);
        if (lane >= d) pre += v;
    }
    if (lane == 63) wsum[wv] = pre;
    __syncthreads();
    int wbase = 0;
#pragma unroll
    for (int w2 = 0; w2 < 4; w2++) wbase += (w2 < wv) ? wsum[w2] : 0;
    int p = wbase + pre - cnt;

    unsigned wrd[4] = {w4.x, w4.y, w4.z, w4.w};
#pragma unroll
    for (int c = 0; c < 4; c++) {
#pragma unroll
        for (int k = 0; k < 4; k++) {
            if ((wrd[c] >> (8 * k)) & 1) {
                if (p < 64) bagl[p] = 16 * tid + 4 * c + k;
                p++;
            }
        }
    }
    __syncthreads();

    if (tid < 64) out_bag[(size_t)b * 64 + tid] = (float)bagl[tid];

    const float4* tab4 = (const float4*)emb_table;
    float4* dst4 = (float4*)(out_emb + (size_t)b * (MAXLEN * EMB));
    for (int q = tid; q < MAXLEN * 5; q += 256) {
        int t = q / 5;
        int m = q - t * 5;
        int row = bagl[t];
        dst4[q] = tab4[row * 5 + m];
    }
}

// ---------------- Kernel 2: packed RNN ----------------
// amdgpu_waves_per_eu(4,4): max waves == min waves, so the allocator has NO
// incentive to squeeze VGPRs below 128 for a higher occupancy step -> the 52
// weight floats stay register-resident (R4/R5 chose 52-60 VGPRs and reloaded
// weights every step). 4 accumulators break the 52-long fmac dep chain.
__global__ __launch_bounds__(128)
__attribute__((amdgpu_waves_per_eu(4, 4)))
void rnn_kernel(
    const float* __restrict__ emb, const float* __restrict__ bagf,
    const float* __restrict__ W_ih, const float* __restrict__ W_hh,
    const float* __restrict__ b_ih, const float* __restrict__ b_hh,
    float* __restrict__ out_h)
{
    __shared__ float hbuf[4][32];   // row per sample; 2 rows per wave (disjoint)

    const int tid = threadIdx.x;
    const int ib  = tid >> 5;          // sample slot 0..3
    const int j   = tid & 31;          // hidden unit
    const int b   = blockIdx.x * 4 + ib;

    float wih[EMB];
#pragma unroll
    for (int k = 0; k < EMB; k++) wih[k] = W_ih[j * EMB + k];
    float whh[HID];
#pragma unroll
    for (int k = 0; k < HID; k++) whh[k] = W_hh[j * HID + k];
    const float sbias = b_ih[j] + b_hh[j];

    // sequence length from sorted bag via one ballot (padding id == 4096)
    const float* bp = bagf + (size_t)b * 64;
    unsigned long long m0 = __ballot(bp[j]      < 4095.5f);
    unsigned long long m1 = __ballot(bp[32 + j] < 4095.5f);
    const int half = ib & 1;
    const int len = __popc((unsigned)(m0 >> (half * 32)))
                  + __popc((unsigned)(m1 >> (half * 32)));

    hbuf[ib][j] = 0.f;
    asm volatile("s_waitcnt lgkmcnt(0)" ::: "memory");   // wave-local fence

    float h = 0.f;
    const float* xb = emb + (size_t)b * (MAXLEN * EMB);

    for (int t = 0; t < MAXLEN; t++) {
        const float4* xp = (const float4*)(xb + t * EMB);
        float4 x0 = xp[0], x1 = xp[1], x2 = xp[2], x3 = xp[3], x4 = xp[4];

        // 4 accumulators: dep chain 52*4cyc -> ~13*4cyc
        float s0 = sbias, s1 = 0.f, s2 = 0.f, s3 = 0.f;
        const float4* hb4 = (const float4*)hbuf[ib];
        float4 hv0 = hb4[0], hv1 = hb4[1], hv2 = hb4[2], hv3 = hb4[3];
        float4 hv4 = hb4[4], hv5 = hb4[5], hv6 = hb4[6], hv7 = hb4[7];

        s0 += whh[0]*hv0.x + whh[1]*hv0.y + whh[2]*hv0.z + whh[3]*hv0.w;
        s1 += whh[4]*hv1.x + whh[5]*hv1.y + whh[6]*hv1.z + whh[7]*hv1.w;
        s2 += whh[8]*hv2.x + whh[9]*hv2.y + whh[10]*hv2.z + whh[11]*hv2.w;
        s3 += whh[12]*hv3.x + whh[13]*hv3.y + whh[14]*hv3.z + whh[15]*hv3.w;
        s0 += whh[16]*hv4.x + whh[17]*hv4.y + whh[18]*hv4.z + whh[19]*hv4.w;
        s1 += whh[20]*hv5.x + whh[21]*hv5.y + whh[22]*hv5.z + whh[23]*hv5.w;
        s2 += whh[24]*hv6.x + whh[25]*hv6.y + whh[26]*hv6.z + whh[27]*hv6.w;
        s3 += whh[28]*hv7.x + whh[29]*hv7.y + whh[30]*hv7.z + whh[31]*hv7.w;

        s0 += wih[0]*x0.x + wih[1]*x0.y + wih[2]*x0.z + wih[3]*x0.w;
        s1 += wih[4]*x1.x + wih[5]*x1.y + wih[6]*x1.z + wih[7]*x1.w;
        s2 += wih[8]*x2.x + wih[9]*x2.y + wih[10]*x2.z + wih[11]*x2.w;
        s3 += wih[12]*x3.x + wih[13]*x3.y + wih[14]*x3.z + wih[15]*x3.w;
        s0 += wih[16]*x4.x + wih[17]*x4.y + wih[18]*x4.z + wih[19]*x4.w;

        float s = (s0 + s1) + (s2 + s3);

        // fast tanh: (e^{2s}-1)/(e^{2s}+1), clamped so exp never overflows
        s = fminf(fmaxf(s, -9.f), 9.f);
        float e = __expf(2.f * s);
        float th = (e - 1.f) * __builtin_amdgcn_rcpf(e + 1.f);

        h = (t < len) ? th : h;            // freeze past sequence length

        hbuf[ib][j] = h;
        asm volatile("s_waitcnt lgkmcnt(0)" ::: "memory");
    }

    out_h[(size_t)b * HID + j] = h;
}

extern "C" void kernel_launch(void* const* d_in, const int* in_sizes, int n_in,
                              void* d_out, int out_size, void* d_ws, size_t ws_size,
                              hipStream_t stream) {
    const int*   chars     = (const int*)d_in[0];
    const int*   colors    = (const int*)d_in[1];
    const float* emb_table = (const float*)d_in[2];
    const float* W_ih      = (const float*)d_in[3];
    const float* W_hh      = (const float*)d_in[4];
    const float* b_ih      = (const float*)d_in[5];
    const float* b_hh      = (const float*)d_in[6];

    const int B = in_sizes[0] / HW;      // 8192

    float* out     = (float*)d_out;
    float* out_h   = out;                                    // [B, 32]
    float* out_emb = out + (size_t)B * HID;                  // [B, 64, 20]
    float* out_bag = out_emb + (size_t)B * MAXLEN * EMB;     // [B, 64]

    bag_emb_kernel<<<B, 256, 0, stream>>>(chars, colors, emb_table, out_emb, out_bag);
    rnn_kernel<<<B / 4, 128, 0, stream>>>(out_emb, out_bag, W_ih, W_hh, b_ih, b_hh, out_h);
}

// Round 7
// 196.123 us; speedup vs baseline: 1.0704x; 1.0704x over previous
//
#include <hip/hip_runtime.h>

#define HW 1659      // 21*79
#define PADID 4096
#define EMB 20
#define HID 32
#define MAXLEN 64

// ---------------- Kernel 0: proj[g][j] = emb_table[g] . W_ih[j]  ---------------
// 4097x32 fp32 (524 KB) into d_ws. Folds the entire x@W_ih.T out of the RNN.
__global__ __launch_bounds__(128) void proj_kernel(
    const float* __restrict__ emb_table, const float* __restrict__ W_ih,
    float* __restrict__ proj)
{
    const int tid = threadIdx.x;
    const int g = blockIdx.x * 4 + (tid >> 5);
    const int j = tid & 31;
    if (g > PADID) return;               // 4097 rows (row 4096 = zeros)
    const float* er = emb_table + (size_t)g * EMB;
    const float* wr = W_ih + j * EMB;
    float s = 0.f;
#pragma unroll
    for (int k = 0; k < EMB; k++) s += wr[k] * er[k];
    proj[(size_t)g * HID + j] = s;
}

// ---------------- Kernel 1: presence bytes -> scan -> bag -> emb gather --------
// (unchanged from R4 — proven)
__global__ __launch_bounds__(256) void bag_emb_kernel(
    const int* __restrict__ chars, const int* __restrict__ colors,
    const float* __restrict__ emb_table,
    float* __restrict__ out_emb, float* __restrict__ out_bag)
{
    __shared__ unsigned char pres[4096];
    __shared__ int bagl[64];
    __shared__ int wsum[4];

    const int b   = blockIdx.x;
    const int tid = threadIdx.x;
    const int lane = tid & 63;
    const int wv   = tid >> 6;

    ((uint4*)pres)[tid] = make_uint4(0u, 0u, 0u, 0u);
    if (tid < 64) bagl[tid] = PADID;
    __syncthreads();

    const int base = b * HW;
    const int pe = (4 - (base & 3)) & 3;          // peel to 16B alignment
    if (tid < pe) {
        int g = (chars[base + tid] << 4) + colors[base + tid];
        pres[g] = 1;
    }
    const int nv = (HW - pe) >> 2;
    const int nt = HW - pe - (nv << 2);
    const int4* c4 = (const int4*)(chars + base + pe);
    const int4* k4 = (const int4*)(colors + base + pe);
    for (int v = tid; v < nv; v += 256) {
        int4 c = c4[v], k = k4[v];
        pres[(c.x << 4) + k.x] = 1;
        pres[(c.y << 4) + k.y] = 1;
        pres[(c.z << 4) + k.z] = 1;
        pres[(c.w << 4) + k.w] = 1;
    }
    if (tid < nt) {
        int i = base + pe + (nv << 2) + tid;
        pres[(chars[i] << 4) + colors[i]] = 1;
    }
    __syncthreads();

    uint4 w4 = ((const uint4*)pres)[tid];
    const unsigned M = 0x01010101u;
    int cnt = __popc(w4.x & M) + __popc(w4.y & M)
            + __popc(w4.z & M) + __popc(w4.w & M);

    int pre = cnt;
#pragma unroll
    for (int d = 1; d < 64; d <<= 1) {
        int v = __shfl_up(pre, d, 64);
        if (lane >= d) pre += v;
    }
    if (lane == 63) wsum[wv] = pre;
    __syncthreads();
    int wbase = 0;
#pragma unroll
    for (int w2 = 0; w2 < 4; w2++) wbase += (w2 < wv) ? wsum[w2] : 0;
    int p = wbase + pre - cnt;

    unsigned wrd[4] = {w4.x, w4.y, w4.z, w4.w};
#pragma unroll
    for (int c = 0; c < 4; c++) {
#pragma unroll
        for (int k = 0; k < 4; k++) {
            if ((wrd[c] >> (8 * k)) & 1) {
                if (p < 64) bagl[p] = 16 * tid + 4 * c + k;
                p++;
            }
        }
    }
    __syncthreads();

    if (tid < 64) out_bag[(size_t)b * 64 + tid] = (float)bagl[tid];

    const float4* tab4 = (const float4*)emb_table;
    float4* dst4 = (float4*)(out_emb + (size_t)b * (MAXLEN * EMB));
    for (int q = tid; q < MAXLEN * 5; q += 256) {
        int t = q / 5;
        int m = q - t * 5;
        int row = bagl[t];
        dst4[q] = tab4[row * 5 + m];
    }
}

// ---------------- Kernel 2: packed RNN with precomputed input projection ------
// R4's exact proven launch config. Per step: 1 coalesced proj load + 32 FMA
// (was: 5 broadcast x loads + 52 FMA). h wave-private; lgkmcnt fence, no barrier.
__global__ __launch_bounds__(128, 4) void rnn_kernel(
    const float* __restrict__ proj, const float* __restrict__ bagf,
    const float* __restrict__ W_hh,
    const float* __restrict__ b_ih, const float* __restrict__ b_hh,
    float* __restrict__ out_h)
{
    __shared__ float hbuf[4][32];   // row per sample; 2 rows per wave (disjoint)

    const int tid = threadIdx.x;
    const int ib  = tid >> 5;          // sample slot 0..3
    const int j   = tid & 31;          // hidden unit
    const int b   = blockIdx.x * 4 + ib;

    float whh[HID];
#pragma unroll
    for (int k = 0; k < HID; k++) whh[k] = W_hh[j * HID + k];
    const float sbias = b_ih[j] + b_hh[j];

    // sequence length from sorted bag via one ballot (padding id == 4096)
    const float* bp = bagf + (size_t)b * 64;
    unsigned long long m0 = __ballot(bp[j]      < 4095.5f);
    unsigned long long m1 = __ballot(bp[32 + j] < 4095.5f);
    const int half = ib & 1;
    const int len = __popc((unsigned)(m0 >> (half * 32)))
                  + __popc((unsigned)(m1 >> (half * 32)));

    hbuf[ib][j] = 0.f;
    asm volatile("s_waitcnt lgkmcnt(0)" ::: "memory");   // wave-local fence

    float h = 0.f;
    for (int t = 0; t < MAXLEN; t++) {
        // proj row for this step: bag value broadcast-load, row load coalesced
        const int idx = (int)bp[t];                       // exact small int
        const float pv = proj[(size_t)idx * HID + j];     // issued early

        float s = sbias + pv;
        const float4* hb4 = (const float4*)hbuf[ib];
#pragma unroll
        for (int m = 0; m < 8; m++) {
            float4 hv = hb4[m];
            s += whh[4*m+0]*hv.x + whh[4*m+1]*hv.y
               + whh[4*m+2]*hv.z + whh[4*m+3]*hv.w;
        }

        // fast tanh: (e^{2s}-1)/(e^{2s}+1), clamped so exp never overflows
        s = fminf(fmaxf(s, -9.f), 9.f);
        float e = __expf(2.f * s);
        float th = (e - 1.f) * __builtin_amdgcn_rcpf(e + 1.f);

        h = (t < len) ? th : h;            // freeze past sequence length

        hbuf[ib][j] = h;
        asm volatile("s_waitcnt lgkmcnt(0)" ::: "memory");
    }

    out_h[(size_t)b * HID + j] = h;
}

// ---------------- Fallback RNN (R4 exact) if ws can't hold proj ----------------
__global__ __launch_bounds__(128, 4) void rnn_kernel_noproj(
    const float* __restrict__ emb, const float* __restrict__ bagf,
    const float* __restrict__ W_ih, const float* __restrict__ W_hh,
    const float* __restrict__ b_ih, const float* __restrict__ b_hh,
    float* __restrict__ out_h)
{
    __shared__ float hbuf[4][32];
    const int tid = threadIdx.x;
    const int ib  = tid >> 5;
    const int j   = tid & 31;
    const int b   = blockIdx.x * 4 + ib;

    float wih[EMB];
#pragma unroll
    for (int k = 0; k < EMB; k++) wih[k] = W_ih[j * EMB + k];
    float whh[HID];
#pragma unroll
    for (int k = 0; k < HID; k++) whh[k] = W_hh[j * HID + k];
    const float sbias = b_ih[j] + b_hh[j];

    const float* bp = bagf + (size_t)b * 64;
    unsigned long long m0 = __ballot(bp[j]      < 4095.5f);
    unsigned long long m1 = __ballot(bp[32 + j] < 4095.5f);
    const int half = ib & 1;
    const int len = __popc((unsigned)(m0 >> (half * 32)))
                  + __popc((unsigned)(m1 >> (half * 32)));

    hbuf[ib][j] = 0.f;
    asm volatile("s_waitcnt lgkmcnt(0)" ::: "memory");

    float h = 0.f;
    const float* xb = emb + (size_t)b * (MAXLEN * EMB);
    for (int t = 0; t < MAXLEN; t++) {
        const float4* xp = (const float4*)(xb + t * EMB);
        float4 x0 = xp[0], x1 = xp[1], x2 = xp[2], x3 = xp[3], x4 = xp[4];
        float s = sbias;
        const float4* hb4 = (const float4*)hbuf[ib];
#pragma unroll
        for (int m = 0; m < 8; m++) {
            float4 hv = hb4[m];
            s += whh[4*m+0]*hv.x + whh[4*m+1]*hv.y
               + whh[4*m+2]*hv.z + whh[4*m+3]*hv.w;
        }
        s += wih[0]*x0.x + wih[1]*x0.y + wih[2]*x0.z + wih[3]*x0.w;
        s += wih[4]*x1.x + wih[5]*x1.y + wih[6]*x1.z + wih[7]*x1.w;
        s += wih[8]*x2.x + wih[9]*x2.y + wih[10]*x2.z + wih[11]*x2.w;
        s += wih[12]*x3.x + wih[13]*x3.y + wih[14]*x3.z + wih[15]*x3.w;
        s += wih[16]*x4.x + wih[17]*x4.y + wih[18]*x4.z + wih[19]*x4.w;
        s = fminf(fmaxf(s, -9.f), 9.f);
        float e = __expf(2.f * s);
        float th = (e - 1.f) * __builtin_amdgcn_rcpf(e + 1.f);
        h = (t < len) ? th : h;
        hbuf[ib][j] = h;
        asm volatile("s_waitcnt lgkmcnt(0)" ::: "memory");
    }
    out_h[(size_t)b * HID + j] = h;
}

extern "C" void kernel_launch(void* const* d_in, const int* in_sizes, int n_in,
                              void* d_out, int out_size, void* d_ws, size_t ws_size,
                              hipStream_t stream) {
    const int*   chars     = (const int*)d_in[0];
    const int*   colors    = (const int*)d_in[1];
    const float* emb_table = (const float*)d_in[2];
    const float* W_ih      = (const float*)d_in[3];
    const float* W_hh      = (const float*)d_in[4];
    const float* b_ih      = (const float*)d_in[5];
    const float* b_hh      = (const float*)d_in[6];

    const int B = in_sizes[0] / HW;      // 8192

    float* out     = (float*)d_out;
    float* out_h   = out;                                    // [B, 32]
    float* out_emb = out + (size_t)B * HID;                  // [B, 64, 20]
    float* out_bag = out_emb + (size_t)B * MAXLEN * EMB;     // [B, 64]

    const size_t proj_bytes = (size_t)(PADID + 1) * HID * sizeof(float);

    bag_emb_kernel<<<B, 256, 0, stream>>>(chars, colors, emb_table, out_emb, out_bag);

    if (ws_size >= proj_bytes) {         // ws_size is fixed -> same path every call
        float* proj = (float*)d_ws;
        proj_kernel<<<(PADID + 1 + 3) / 4, 128, 0, stream>>>(emb_table, W_ih, proj);
        rnn_kernel<<<B / 4, 128, 0, stream>>>(proj, out_bag, W_hh, b_ih, b_hh, out_h);
    } else {
        rnn_kernel_noproj<<<B / 4, 128, 0, stream>>>(out_emb, out_bag, W_ih, W_hh,
                                                     b_ih, b_hh, out_h);
    }
}

// Round 8
// 186.471 us; speedup vs baseline: 1.1258x; 1.0518x over previous
//
#include <hip/hip_runtime.h>

#define HW 1659      // 21*79
#define PADID 4096
#define EMB 20
#define HID 32
#define MAXLEN 64

// ---------------- Kernel 0: proj[g][j] = emb_table[g] . W_ih[j]  ---------------
__global__ __launch_bounds__(128) void proj_kernel(
    const float* __restrict__ emb_table, const float* __restrict__ W_ih,
    float* __restrict__ proj)
{
    const int tid = threadIdx.x;
    const int g = blockIdx.x * 4 + (tid >> 5);
    const int j = tid & 31;
    if (g > PADID) return;               // 4097 rows (row 4096 = zeros)
    const float* er = emb_table + (size_t)g * EMB;
    const float* wr = W_ih + j * EMB;
    float s = 0.f;
#pragma unroll
    for (int k = 0; k < EMB; k++) s += wr[k] * er[k];
    proj[(size_t)g * HID + j] = s;
}

// ---------------- Kernel 1: presence bytes -> scan -> bag -> emb gather --------
// (unchanged — proven)
__global__ __launch_bounds__(256) void bag_emb_kernel(
    const int* __restrict__ chars, const int* __restrict__ colors,
    const float* __restrict__ emb_table,
    float* __restrict__ out_emb, float* __restrict__ out_bag)
{
    __shared__ unsigned char pres[4096];
    __shared__ int bagl[64];
    __shared__ int wsum[4];

    const int b   = blockIdx.x;
    const int tid = threadIdx.x;
    const int lane = tid & 63;
    const int wv   = tid >> 6;

    ((uint4*)pres)[tid] = make_uint4(0u, 0u, 0u, 0u);
    if (tid < 64) bagl[tid] = PADID;
    __syncthreads();

    const int base = b * HW;
    const int pe = (4 - (base & 3)) & 3;          // peel to 16B alignment
    if (tid < pe) {
        int g = (chars[base + tid] << 4) + colors[base + tid];
        pres[g] = 1;
    }
    const int nv = (HW - pe) >> 2;
    const int nt = HW - pe - (nv << 2);
    const int4* c4 = (const int4*)(chars + base + pe);
    const int4* k4 = (const int4*)(colors + base + pe);
    for (int v = tid; v < nv; v += 256) {
        int4 c = c4[v], k = k4[v];
        pres[(c.x << 4) + k.x] = 1;
        pres[(c.y << 4) + k.y] = 1;
        pres[(c.z << 4) + k.z] = 1;
        pres[(c.w << 4) + k.w] = 1;
    }
    if (tid < nt) {
        int i = base + pe + (nv << 2) + tid;
        pres[(chars[i] << 4) + colors[i]] = 1;
    }
    __syncthreads();

    uint4 w4 = ((const uint4*)pres)[tid];
    const unsigned M = 0x01010101u;
    int cnt = __popc(w4.x & M) + __popc(w4.y & M)
            + __popc(w4.z & M) + __popc(w4.w & M);

    int pre = cnt;
#pragma unroll
    for (int d = 1; d < 64; d <<= 1) {
        int v = __shfl_up(pre, d, 64);
        if (lane >= d) pre += v;
    }
    if (lane == 63) wsum[wv] = pre;
    __syncthreads();
    int wbase = 0;
#pragma unroll
    for (int w2 = 0; w2 < 4; w2++) wbase += (w2 < wv) ? wsum[w2] : 0;
    int p = wbase + pre - cnt;

    unsigned wrd[4] = {w4.x, w4.y, w4.z, w4.w};
#pragma unroll
    for (int c = 0; c < 4; c++) {
#pragma unroll
        for (int k = 0; k < 4; k++) {
            if ((wrd[c] >> (8 * k)) & 1) {
                if (p < 64) bagl[p] = 16 * tid + 4 * c + k;
                p++;
            }
        }
    }
    __syncthreads();

    if (tid < 64) out_bag[(size_t)b * 64 + tid] = (float)bagl[tid];

    const float4* tab4 = (const float4*)emb_table;
    float4* dst4 = (float4*)(out_emb + (size_t)b * (MAXLEN * EMB));
    for (int q = tid; q < MAXLEN * 5; q += 256) {
        int t = q / 5;
        int m = q - t * 5;
        int row = bagl[t];
        dst4[q] = tab4[row * 5 + m];
    }
}

// ---------------- Kernel 2: packed RNN, fully prefetched inputs ----------------
// All 64 proj values prefetched to VGPRs (2 chunks of 32) BEFORE the loop:
// the loop body has ZERO global loads, so the memory-clobber fence no longer
// serializes load latency. LDS h-exchange unchanged (discriminates T1 vs T2).
__global__ __launch_bounds__(128, 4) void rnn_kernel(
    const float* __restrict__ proj, const float* __restrict__ bagf,
    const float* __restrict__ W_hh,
    const float* __restrict__ b_ih, const float* __restrict__ b_hh,
    float* __restrict__ out_h)
{
    __shared__ float hbuf[4][32];   // row per sample; 2 rows per wave (disjoint)

    const int tid = threadIdx.x;
    const int ib  = tid >> 5;          // sample slot 0..3
    const int j   = tid & 31;          // hidden unit
    const int b   = blockIdx.x * 4 + ib;

    float whh[HID];
#pragma unroll
    for (int k = 0; k < HID; k++) whh[k] = W_hh[j * HID + k];
    const float sbias = b_ih[j] + b_hh[j];

    const float* bp = bagf + (size_t)b * 64;

    // ---- prefetch chunk A: t = 0..31 ----
    float pvA[32]; int lenA = 0;
    {
        int idx[32];
#pragma unroll
        for (int t = 0; t < 32; t++) idx[t] = (int)bp[t];
#pragma unroll
        for (int t = 0; t < 32; t++) {
            lenA += (idx[t] < PADID) ? 1 : 0;
            pvA[t] = proj[idx[t] * HID + j];      // row 4096 is all zeros
        }
    }

    hbuf[ib][j] = 0.f;
    asm volatile("s_waitcnt lgkmcnt(0)" ::: "memory");   // wave-local fence

    float h = 0.f;
    const float* hb = hbuf[ib];

#pragma unroll
    for (int t = 0; t < 32; t++) {
        const float4* hb4 = (const float4*)hb;
        float s0 = sbias + pvA[t], s1 = 0.f;
#pragma unroll
        for (int m = 0; m < 4; m++) {
            float4 hv0 = hb4[2*m], hv1 = hb4[2*m+1];
            s0 += whh[8*m+0]*hv0.x + whh[8*m+1]*hv0.y
                + whh[8*m+2]*hv0.z + whh[8*m+3]*hv0.w;
            s1 += whh[8*m+4]*hv1.x + whh[8*m+5]*hv1.y
                + whh[8*m+6]*hv1.z + whh[8*m+7]*hv1.w;
        }
        float s = s0 + s1;
        s = fminf(fmaxf(s, -9.f), 9.f);
        float e = __expf(2.f * s);
        float th = (e - 1.f) * __builtin_amdgcn_rcpf(e + 1.f);
        h = (t < lenA) ? th : h;           // exact for t<32 (bag sorted)
        hbuf[ib][j] = h;
        asm volatile("s_waitcnt lgkmcnt(0)" ::: "memory");
    }

    // ---- prefetch chunk B: t = 32..63 (one-time exposed latency) ----
    float pvB[32]; int lenB = 0;
    {
        int idx[32];
#pragma unroll
        for (int t = 0; t < 32; t++) idx[t] = (int)bp[32 + t];
#pragma unroll
        for (int t = 0; t < 32; t++) {
            lenB += (idx[t] < PADID) ? 1 : 0;
            pvB[t] = proj[idx[t] * HID + j];
        }
    }
    const int len = lenA + lenB;           // exact (sorted: lenA<32 => lenB==0)

#pragma unroll
    for (int t2 = 0; t2 < 32; t2++) {
        const int t = 32 + t2;
        const float4* hb4 = (const float4*)hb;
        float s0 = sbias + pvB[t2], s1 = 0.f;
#pragma unroll
        for (int m = 0; m < 4; m++) {
            float4 hv0 = hb4[2*m], hv1 = hb4[2*m+1];
            s0 += whh[8*m+0]*hv0.x + whh[8*m+1]*hv0.y
                + whh[8*m+2]*hv0.z + whh[8*m+3]*hv0.w;
            s1 += whh[8*m+4]*hv1.x + whh[8*m+5]*hv1.y
                + whh[8*m+6]*hv1.z + whh[8*m+7]*hv1.w;
        }
        float s = s0 + s1;
        s = fminf(fmaxf(s, -9.f), 9.f);
        float e = __expf(2.f * s);
        float th = (e - 1.f) * __builtin_amdgcn_rcpf(e + 1.f);
        h = (t < len) ? th : h;
        hbuf[ib][j] = h;
        asm volatile("s_waitcnt lgkmcnt(0)" ::: "memory");
    }

    out_h[(size_t)b * HID + j] = h;
}

// ---------------- Fallback RNN (R4 exact) if ws can't hold proj ----------------
__global__ __launch_bounds__(128, 4) void rnn_kernel_noproj(
    const float* __restrict__ emb, const float* __restrict__ bagf,
    const float* __restrict__ W_ih, const float* __restrict__ W_hh,
    const float* __restrict__ b_ih, const float* __restrict__ b_hh,
    float* __restrict__ out_h)
{
    __shared__ float hbuf[4][32];
    const int tid = threadIdx.x;
    const int ib  = tid >> 5;
    const int j   = tid & 31;
    const int b   = blockIdx.x * 4 + ib;

    float wih[EMB];
#pragma unroll
    for (int k = 0; k < EMB; k++) wih[k] = W_ih[j * EMB + k];
    float whh[HID];
#pragma unroll
    for (int k = 0; k < HID; k++) whh[k] = W_hh[j * HID + k];
    const float sbias = b_ih[j] + b_hh[j];

    const float* bp = bagf + (size_t)b * 64;
    unsigned long long m0 = __ballot(bp[j]      < 4095.5f);
    unsigned long long m1 = __ballot(bp[32 + j] < 4095.5f);
    const int half = ib & 1;
    const int len = __popc((unsigned)(m0 >> (half * 32)))
                  + __popc((unsigned)(m1 >> (half * 32)));

    hbuf[ib][j] = 0.f;
    asm volatile("s_waitcnt lgkmcnt(0)" ::: "memory");

    float h = 0.f;
    const float* xb = emb + (size_t)b * (MAXLEN * EMB);
    for (int t = 0; t < MAXLEN; t++) {
        const float4* xp = (const float4*)(xb + t * EMB);
        float4 x0 = xp[0], x1 = xp[1], x2 = xp[2], x3 = xp[3], x4 = xp[4];
        float s = sbias;
        const float4* hb4 = (const float4*)hbuf[ib];
#pragma unroll
        for (int m = 0; m < 8; m++) {
            float4 hv = hb4[m];
            s += whh[4*m+0]*hv.x + whh[4*m+1]*hv.y
               + whh[4*m+2]*hv.z + whh[4*m+3]*hv.w;
        }
        s += wih[0]*x0.x + wih[1]*x0.y + wih[2]*x0.z + wih[3]*x0.w;
        s += wih[4]*x1.x + wih[5]*x1.y + wih[6]*x1.z + wih[7]*x1.w;
        s += wih[8]*x2.x + wih[9]*x2.y + wih[10]*x2.z + wih[11]*x2.w;
        s += wih[12]*x3.x + wih[13]*x3.y + wih[14]*x3.z + wih[15]*x3.w;
        s += wih[16]*x4.x + wih[17]*x4.y + wih[18]*x4.z + wih[19]*x4.w;
        s = fminf(fmaxf(s, -9.f), 9.f);
        float e = __expf(2.f * s);
        float th = (e - 1.f) * __builtin_amdgcn_rcpf(e + 1.f);
        h = (t < len) ? th : h;
        hbuf[ib][j] = h;
        asm volatile("s_waitcnt lgkmcnt(0)" ::: "memory");
    }
    out_h[(size_t)b * HID + j] = h;
}

extern "C" void kernel_launch(void* const* d_in, const int* in_sizes, int n_in,
                              void* d_out, int out_size, void* d_ws, size_t ws_size,
                              hipStream_t stream) {
    const int*   chars     = (const int*)d_in[0];
    const int*   colors    = (const int*)d_in[1];
    const float* emb_table = (const float*)d_in[2];
    const float* W_ih      = (const float*)d_in[3];
    const float* W_hh      = (const float*)d_in[4];
    const float* b_ih      = (const float*)d_in[5];
    const float* b_hh      = (const float*)d_in[6];

    const int B = in_sizes[0] / HW;      // 8192

    float* out     = (float*)d_out;
    float* out_h   = out;                                    // [B, 32]
    float* out_emb = out + (size_t)B * HID;                  // [B, 64, 20]
    float* out_bag = out_emb + (size_t)B * MAXLEN * EMB;     // [B, 64]

    const size_t proj_bytes = (size_t)(PADID + 1) * HID * sizeof(float);

    bag_emb_kernel<<<B, 256, 0, stream>>>(chars, colors, emb_table, out_emb, out_bag);

    if (ws_size >= proj_bytes) {         // ws_size is fixed -> same path every call
        float* proj = (float*)d_ws;
        proj_kernel<<<(PADID + 1 + 3) / 4, 128, 0, stream>>>(emb_table, W_ih, proj);
        rnn_kernel<<<B / 4, 128, 0, stream>>>(proj, out_bag, W_hh, b_ih, b_hh, out_h);
    } else {
        rnn_kernel_noproj<<<B / 4, 128, 0, stream>>>(out_emb, out_bag, W_ih, W_hh,
                                                     b_ih, b_hh, out_h);
    }
}